// Round 1
// baseline (116.522 us; speedup 1.0000x reference)
//
#include <hip/hip_runtime.h>
#include <math.h>

#define BATCH 64
#define CH    256
#define RCH   64
#define HW    3136          // 56*56
#define HW4   784           // HW/4 float4 per plane

// ---------------- Kernel 1: global average pool ----------------
// One block per (b,c) plane. 256 threads, float4 loads, wave+LDS reduce.
__global__ __launch_bounds__(256) void se_pool(const float* __restrict__ x,
                                               float* __restrict__ s) {
    const int plane = blockIdx.x;                 // b*CH + c
    const float4* __restrict__ p4 =
        reinterpret_cast<const float4*>(x + (size_t)plane * HW);
    const int tid = threadIdx.x;

    float acc = 0.0f;
    #pragma unroll
    for (int i = tid; i < HW4; i += 256) {
        float4 v = p4[i];
        acc += (v.x + v.y) + (v.z + v.w);
    }
    // wave(64) shuffle reduce
    #pragma unroll
    for (int off = 32; off > 0; off >>= 1)
        acc += __shfl_down(acc, off, 64);

    __shared__ float red[4];
    const int wave = tid >> 6;
    if ((tid & 63) == 0) red[wave] = acc;
    __syncthreads();
    if (tid == 0) {
        float t = (red[0] + red[1]) + (red[2] + red[3]);
        s[plane] = t * (1.0f / (float)HW);
    }
}

// ---------------- Kernel 2: excite (two tiny dense layers) ----------------
// One block per batch element, 256 threads.
__global__ __launch_bounds__(256) void se_excite(const float* __restrict__ s,
                                                 const float* __restrict__ w1,
                                                 const float* __restrict__ b1,
                                                 const float* __restrict__ w2,
                                                 const float* __restrict__ b2,
                                                 float* __restrict__ g) {
    const int b   = blockIdx.x;
    const int tid = threadIdx.x;

    __shared__ float sv[CH];
    __shared__ float hv[RCH];

    sv[tid] = s[b * CH + tid];
    __syncthreads();

    if (tid < RCH) {
        float acc = b1[tid];
        const float* __restrict__ w = w1 + tid * CH;
        #pragma unroll 8
        for (int c = 0; c < CH; ++c) acc = fmaf(w[c], sv[c], acc);
        hv[tid] = fmaxf(acc, 0.0f);
    }
    __syncthreads();

    float acc = b2[tid];
    const float* __restrict__ w = w2 + tid * RCH;
    #pragma unroll 8
    for (int r = 0; r < RCH; ++r) acc = fmaf(w[r], hv[r], acc);
    g[b * CH + tid] = 1.0f / (1.0f + expf(-acc));
}

// ---------------- Kernel 3: broadcast scale ----------------
// One block per (b,c) plane; scalar g broadcast, float4 RMW.
__global__ __launch_bounds__(256) void se_scale(const float* __restrict__ x,
                                                const float* __restrict__ g,
                                                float* __restrict__ out) {
    const int plane = blockIdx.x;
    const float gg = g[plane];                    // wave-uniform scalar load
    const float4* __restrict__ x4 =
        reinterpret_cast<const float4*>(x + (size_t)plane * HW);
    float4* __restrict__ o4 =
        reinterpret_cast<float4*>(out + (size_t)plane * HW);
    const int tid = threadIdx.x;

    #pragma unroll
    for (int i = tid; i < HW4; i += 256) {
        float4 v = x4[i];
        v.x *= gg; v.y *= gg; v.z *= gg; v.w *= gg;
        o4[i] = v;
    }
}

extern "C" void kernel_launch(void* const* d_in, const int* in_sizes, int n_in,
                              void* d_out, int out_size, void* d_ws, size_t ws_size,
                              hipStream_t stream) {
    const float* x  = (const float*)d_in[0];
    const float* w1 = (const float*)d_in[1];
    const float* b1 = (const float*)d_in[2];
    const float* w2 = (const float*)d_in[3];
    const float* b2 = (const float*)d_in[4];
    float* out = (float*)d_out;

    float* s = (float*)d_ws;                       // BATCH*CH floats = 64 KB
    float* g = s + BATCH * CH;                     // BATCH*CH floats = 64 KB

    const int nplanes = BATCH * CH;                // 16384

    se_pool<<<nplanes, 256, 0, stream>>>(x, s);
    se_excite<<<BATCH, 256, 0, stream>>>(s, w1, b1, w2, b2, g);
    se_scale<<<nplanes, 256, 0, stream>>>(x, g, out);
}

// Round 2
// 102.992 us; speedup vs baseline: 1.1314x; 1.1314x over previous
//
#include <hip/hip_runtime.h>
#include <math.h>

#define BATCH 64
#define CH    256
#define RCH   64
#define HW    3136          // 56*56
#define HW4   784           // HW/4 float4 per plane

typedef float f4 __attribute__((ext_vector_type(4)));

// ---------------- Kernel 1: global average pool ----------------
// One WAVE per (b,c) plane; 4 planes per block. Pure shuffle reduce.
// Normal (caching) loads on purpose: populate L3 with x for se_scale.
__global__ __launch_bounds__(256) void se_pool(const float* __restrict__ x,
                                               float* __restrict__ s) {
    const int wave = threadIdx.x >> 6;
    const int lane = threadIdx.x & 63;
    const int plane = blockIdx.x * 4 + wave;      // b*CH + c
    const f4* __restrict__ p4 =
        reinterpret_cast<const f4*>(x + (size_t)plane * HW);

    float acc = 0.0f;
    for (int i = lane; i < HW4; i += 64) {        // 12-13 float4 per lane
        f4 v = p4[i];
        acc += (v.x + v.y) + (v.z + v.w);
    }
    #pragma unroll
    for (int off = 32; off > 0; off >>= 1)
        acc += __shfl_down(acc, off, 64);
    if (lane == 0)
        s[plane] = acc * (1.0f / (float)HW);
}

// ---------------- Kernel 2: excite (two tiny dense layers) ----------------
__global__ __launch_bounds__(256) void se_excite(const float* __restrict__ s,
                                                 const float* __restrict__ w1,
                                                 const float* __restrict__ b1,
                                                 const float* __restrict__ w2,
                                                 const float* __restrict__ b2,
                                                 float* __restrict__ g) {
    const int b   = blockIdx.x;
    const int tid = threadIdx.x;

    __shared__ float sv[CH];
    __shared__ float hv[RCH];

    sv[tid] = s[b * CH + tid];
    __syncthreads();

    if (tid < RCH) {
        float acc = b1[tid];
        const float* __restrict__ w = w1 + tid * CH;
        #pragma unroll 8
        for (int c = 0; c < CH; ++c) acc = fmaf(w[c], sv[c], acc);
        hv[tid] = fmaxf(acc, 0.0f);
    }
    __syncthreads();

    float acc = b2[tid];
    const float* __restrict__ w = w2 + tid * RCH;
    #pragma unroll 8
    for (int r = 0; r < RCH; ++r) acc = fmaf(w[r], hv[r], acc);
    g[b * CH + tid] = 1.0f / (1.0f + expf(-acc));
}

// ---------------- Kernel 3: broadcast scale ----------------
// One block per plane. Reads of x should hit L3 (populated by se_pool);
// NON-TEMPORAL stores for out keep L3 from being evicted by the output.
__global__ __launch_bounds__(256) void se_scale(const float* __restrict__ x,
                                                const float* __restrict__ g,
                                                float* __restrict__ out) {
    const int plane = blockIdx.x;
    const float gg = g[plane];                    // wave-uniform scalar load
    const f4* __restrict__ x4 =
        reinterpret_cast<const f4*>(x + (size_t)plane * HW);
    f4* __restrict__ o4 =
        reinterpret_cast<f4*>(out + (size_t)plane * HW);
    const int tid = threadIdx.x;

    #pragma unroll
    for (int i = tid; i < HW4; i += 256) {
        f4 v = x4[i];
        v.x *= gg; v.y *= gg; v.z *= gg; v.w *= gg;
        __builtin_nontemporal_store(v, o4 + i);
    }
}

extern "C" void kernel_launch(void* const* d_in, const int* in_sizes, int n_in,
                              void* d_out, int out_size, void* d_ws, size_t ws_size,
                              hipStream_t stream) {
    const float* x  = (const float*)d_in[0];
    const float* w1 = (const float*)d_in[1];
    const float* b1 = (const float*)d_in[2];
    const float* w2 = (const float*)d_in[3];
    const float* b2 = (const float*)d_in[4];
    float* out = (float*)d_out;

    float* s = (float*)d_ws;                       // BATCH*CH floats = 64 KB
    float* g = s + BATCH * CH;                     // BATCH*CH floats = 64 KB

    const int nplanes = BATCH * CH;                // 16384

    se_pool<<<nplanes / 4, 256, 0, stream>>>(x, s);
    se_excite<<<BATCH, 256, 0, stream>>>(s, w1, b1, w2, b2, g);
    se_scale<<<nplanes, 256, 0, stream>>>(x, g, out);
}